// Round 7
// baseline (414.721 us; speedup 1.0000x reference)
//
#include <hip/hip_runtime.h>
#include <hip/hip_bf16.h>

#define RMAX 40
#define HH   512
#define WW   512
#define CC   3
#define BB   64
#define ROWS 4     // h-rows per passB block
#define LROW 592   // f16 elements per LDS row (74*8)

typedef unsigned short u16;
typedef __attribute__((ext_vector_type(8))) short short8;   // 8 bf16 MFMA A/B frag
typedef __attribute__((ext_vector_type(4))) float f32x4;    // MFMA C/D frag + 16B loads
typedef _Float16 h2 __attribute__((ext_vector_type(2)));
typedef _Float16 h8 __attribute__((ext_vector_type(8)));
typedef __attribute__((ext_vector_type(8))) u16 u16x8;

// bf16 round-to-nearest-even pack/unpack
__device__ __forceinline__ u16 f2bf(float f) {
    unsigned u = __float_as_uint(f);
    u += 0x7FFFu + ((u >> 16) & 1u);
    return (u16)(u >> 16);
}
__device__ __forceinline__ float bf2f(u16 s) {
    return __uint_as_float(((unsigned)s) << 16);
}
__device__ __forceinline__ u16 h2u16(_Float16 h) { return __builtin_bit_cast(u16, h); }

// f16 dot-pair with fp32 accumulate (v_dot2_f32_f16); fallback keeps correctness
__device__ __forceinline__ float fdot2w(h2 a, unsigned wpk, float c) {
#if __has_builtin(__builtin_amdgcn_fdot2)
    return __builtin_amdgcn_fdot2(a, __builtin_bit_cast(h2, wpk), c, false);
#else
    h2 wv = __builtin_bit_cast(h2, wpk);
    return c + (float)a.x * (float)wv.x + (float)a.y * (float)wv.y;
#endif
}

// ---------------------------------------------------------------------------
// prep: rbuf radius, mbuf 3x3 channel mix, ptab f16 pair-phase weight tables
// for passB's dot2 (E[m]=(kpad[2m],kpad[2m+1]), O[m]=(kpad[2m-1],kpad[2m]),
// kpad[i]=k_{i-56} zero-padded), atab bf16 hi/lo Toeplitz for passC's MFMA.
// ---------------------------------------------------------------------------
__global__ __launch_bounds__(256) void prep_kernel(
    const float* __restrict__ sigmas10,
    const int*   __restrict__ steps,
    int*      __restrict__ rbuf,
    float*    __restrict__ mbuf,
    unsigned* __restrict__ ptab,
    u16*      __restrict__ atab)
{
    const int b   = blockIdx.x;
    const int tid = threadIdx.x;
    const float sigma = sigmas10[steps[b]];
    int r = (int)floorf(4.0f * sigma + 0.5f);
    if (r > RMAX) r = RMAX;
    const float s2 = sigma * sigma;

    float sum = 0.0f;
    for (int p = -r; p <= r; ++p)
        sum += expf(-0.5f * (float)(p * p) / s2);
    const float inv = 1.0f / sum;

    // kpad[i] = k_{i-56} (zero outside support)
    auto kval = [&](int i) -> float {
        int p = i - 56;
        if (p < -r || p > r) return 0.0f;
        return expf(-0.5f * (float)(p * p) / s2) * inv;
    };

    if (tid < 64) {                       // even-paired table E
        float a = kval(2 * tid), bb = kval(2 * tid + 1);
        unsigned pk = (unsigned)h2u16((_Float16)a)
                    | ((unsigned)h2u16((_Float16)bb) << 16);
        ptab[b * 128 + tid] = pk;
    } else if (tid < 128) {               // staggered table O
        int m = tid - 64;
        float a = kval(2 * m - 1), bb = kval(2 * m);
        unsigned pk = (unsigned)h2u16((_Float16)a)
                    | ((unsigned)h2u16((_Float16)bb) << 16);
        ptab[b * 128 + 64 + m] = pk;
    }

    if (tid == 0) {
        rbuf[b] = r;
        float Mm[9];
        for (int i = 0; i < 9; ++i) Mm[i] = 0.0f;
        for (int p = -r; p <= r; ++p) {
            float wv = expf(-0.5f * (float)(p * p) / s2) * inv;
            for (int c = 0; c < CC; ++c) {
                int i = c + p;
                int j = ((i % 6) + 6) % 6;     // reflect n=3 -> period 6
                int cc = (j < 3) ? j : 5 - j;
                Mm[c * 3 + cc] += wv;
            }
        }
        for (int c = 0; c < 3; ++c)
            for (int cc = 0; cc < 3; ++cc)
                mbuf[b * 12 + c * 4 + cc] = Mm[c * 3 + cc];
    }

    // bf16 hi/lo A-fragment table for passC (unchanged layout)
    u16* ab = atab + (size_t)b * 8192;
    int e = tid * 32;
    for (int ee = 0; ee < 32; ++ee, ++e) {
        int j    = e & 7;
        int lane = (e >> 3) & 63;
        int s    = e >> 9;
        int ch   = s >> 2;
        int half = (s >> 1) & 1;
        int prec = s & 1;
        int m = 32 * ch + ((lane >> 4) << 3) + j - (lane & 15) - 16 * half;
        float wfull = 0.0f;
        if (m >= 0 && m <= 2 * r) {
            int p = m - r;
            wfull = expf(-0.5f * (float)(p * p) / s2) * inv;
        }
        u16 hi = f2bf(wfull);
        u16 val = hi;
        if (prec) val = f2bf(wfull - bf2f(hi));
        ab[e] = val;
    }
}

// ---------------------------------------------------------------------------
// passB: channel mix + W-conv. mixed staged as f16 (12 rows x 592, 13.9 KiB
// -> 8 blocks/CU, 32 waves). Compute: 8 outputs/task via v_dot2_f32_f16 with
// pair-phase weight tables (all SGPR); 1 ds_read_b128 per 8 taps x 8 outputs.
// 3 exact tasks/thread. bf16 out, 16B stores.
// R7 FIX: chunk count must cover the q=7 output's tail taps (+7).
// ---------------------------------------------------------------------------
__global__ __launch_bounds__(256) void passB_kernel(
    const float*    __restrict__ x,
    const unsigned* __restrict__ ptab,
    const float*    __restrict__ mbuf,
    const int*      __restrict__ rbuf,
    u16* __restrict__ out1)
{
    __shared__ __align__(16) u16 mixs[CC * ROWS][LROW];   // f16 bits

    const int b   = blockIdx.y;
    const int h0  = blockIdx.x * ROWS;
    const int tid = threadIdx.x;
    const int r   = __builtin_amdgcn_readfirstlane(rbuf[b]);

    const float M00 = mbuf[b * 12 + 0], M01 = mbuf[b * 12 + 1], M02 = mbuf[b * 12 + 2];
    const float M10 = mbuf[b * 12 + 4], M11 = mbuf[b * 12 + 5], M12 = mbuf[b * 12 + 6];
    const float M20 = mbuf[b * 12 + 8], M21 = mbuf[b * 12 + 9], M22 = mbuf[b * 12 + 10];

    const float* xb = x + (size_t)b * CC * HH * WW + (size_t)h0 * WW;

    // interior: 4 rows x 128 float4-groups = 512 tasks, 2 per thread
#pragma unroll
    for (int it = 0; it < 2; ++it) {
        int idx = tid + 256 * it;
        int row = idx >> 7;                  // 0..3
        int w   = (idx & 127) << 2;          // 0..508
        const float* px = xb + (size_t)row * WW + w;
        f32x4 c0 = __builtin_nontemporal_load((const f32x4*)px);
        f32x4 c1 = __builtin_nontemporal_load((const f32x4*)(px + HH * WW));
        f32x4 c2 = __builtin_nontemporal_load((const f32x4*)(px + 2 * HH * WW));
        f32x4 m0 = M00 * c0 + M01 * c1 + M02 * c2;
        f32x4 m1 = M10 * c0 + M11 * c1 + M12 * c2;
        f32x4 m2 = M20 * c0 + M21 * c1 + M22 * c2;
        ushort4 o0, o1, o2;
        o0.x = h2u16((_Float16)m0.x); o0.y = h2u16((_Float16)m0.y);
        o0.z = h2u16((_Float16)m0.z); o0.w = h2u16((_Float16)m0.w);
        o1.x = h2u16((_Float16)m1.x); o1.y = h2u16((_Float16)m1.y);
        o1.z = h2u16((_Float16)m1.z); o1.w = h2u16((_Float16)m1.w);
        o2.x = h2u16((_Float16)m2.x); o2.y = h2u16((_Float16)m2.y);
        o2.z = h2u16((_Float16)m2.z); o2.w = h2u16((_Float16)m2.w);
        *(ushort4*)&mixs[0 * ROWS + row][RMAX + w] = o0;
        *(ushort4*)&mixs[1 * ROWS + row][RMAX + w] = o1;
        *(ushort4*)&mixs[2 * ROWS + row][RMAX + w] = o2;
    }
    // halo: 4 rows x 80 reflected positions = 320
#pragma unroll
    for (int it = 0; it < 2; ++it) {
        int hidx = tid + 256 * it;
        if (hidx < ROWS * 2 * RMAX) {
            int row = hidx & 3;
            int pos = hidx >> 2;                       // 0..79
            int wi  = (pos < RMAX) ? pos : (WW + pos); // [0,40) U [552,592)
            int lw  = wi - RMAX;
            int jm  = lw & (2 * WW - 1);
            int src = (jm < WW) ? jm : (2 * WW - 1 - jm);
            const float* px = xb + (size_t)row * WW + src;
            float a0 = __builtin_nontemporal_load(px);
            float a1 = __builtin_nontemporal_load(px + HH * WW);
            float a2 = __builtin_nontemporal_load(px + 2 * HH * WW);
            mixs[0 * ROWS + row][wi] = h2u16((_Float16)(M00 * a0 + M01 * a1 + M02 * a2));
            mixs[1 * ROWS + row][wi] = h2u16((_Float16)(M10 * a0 + M11 * a1 + M12 * a2));
            mixs[2 * ROWS + row][wi] = h2u16((_Float16)(M20 * a0 + M21 * a1 + M22 * a2));
        }
    }
    __syncthreads();

    // window geometry (all wave-uniform): chunk-aligned start, pair-table base
    const int i0off = (RMAX - r) & ~7;                       // rel. window start
    const int base0 = (16 + i0off) >> 1;                     // pair index base
    // chunks must cover j up to d + 7 + 2r (output q=7's last tap)
    const int nck   = ((((RMAX - r) & 7) + 7 + 2 * r) >> 3) + 1;
    const unsigned* et = ptab + b * 128;
    const unsigned* ot = et + 64;

#pragma unroll
    for (int k = 0; k < 3; ++k) {
        const int task = tid + 256 * k;      // 0..767
        const int g    = task & 63;
        const int rc   = task >> 6;          // 0..11 (c = rc>>2, row = rc&3)
        const int w0   = g << 3;
        const u16* L   = &mixs[rc][0];
        const int ib   = w0 + i0off;

        float a0 = 0.f, a1 = 0.f, a2 = 0.f, a3 = 0.f;
        float a4 = 0.f, a5 = 0.f, a6 = 0.f, a7 = 0.f;

        for (int c = 0; c < nck; ++c) {
            h8 D = *(const h8*)(L + ib + 8 * c);     // ds_read_b128, 8 taps
            int mi = base0 + 4 * c;
#pragma unroll
            for (int u = 0; u < 4; ++u) {
                h2 dp = { D[2 * u], D[2 * u + 1] };  // pair == one VGPR of D
                a0 = fdot2w(dp, et[mi + u],     a0);
                a1 = fdot2w(dp, ot[mi + u],     a1);
                a2 = fdot2w(dp, et[mi + u - 1], a2);
                a3 = fdot2w(dp, ot[mi + u - 1], a3);
                a4 = fdot2w(dp, et[mi + u - 2], a4);
                a5 = fdot2w(dp, ot[mi + u - 2], a5);
                a6 = fdot2w(dp, et[mi + u - 3], a6);
                a7 = fdot2w(dp, ot[mi + u - 3], a7);
            }
        }

        const int cch = rc >> 2, row = rc & 3;
        u16x8 o = { f2bf(a0), f2bf(a1), f2bf(a2), f2bf(a3),
                    f2bf(a4), f2bf(a5), f2bf(a6), f2bf(a7) };
        u16* dst = out1 + ((size_t)b * CC + cch) * HH * WW
                 + (size_t)(h0 + row) * WW + w0;
        *(u16x8*)dst = o;                    // 16B aligned (w0 % 8 == 0)
    }
}

// ---------------------------------------------------------------------------
// passC: H-axis conv as MFMA (unchanged). D = A*B, A = hi/lo bf16 Toeplitz,
// B = inter rows (bf16 row-major).
// ---------------------------------------------------------------------------
__device__ __forceinline__ int refl512(int i) {
    int jm = i & (2 * HH - 1);
    return (jm < HH) ? jm : (2 * HH - 1 - jm);
}

__global__ __launch_bounds__(256) void passC_kernel(
    const u16* __restrict__ in1,
    const u16* __restrict__ atab,
    const int* __restrict__ rbuf,
    float* __restrict__ out)
{
    const int tid  = threadIdx.x;
    const int lane = tid & 63;
    const int bc   = blockIdx.z;
    const int b    = bc / 3;
    const int r    = __builtin_amdgcn_readfirstlane(rbuf[b]);
    const int h0   = blockIdx.y * 32;
    const int w    = blockIdx.x * 64 + (tid >> 6) * 16 + (lane & 15);
    const int nch  = (2 * r + 63) >> 5;
    const int rowbase = h0 - r + ((lane >> 4) << 3);

    const u16* src = in1 + (size_t)bc * HH * WW + w;
    const short8* at = (const short8*)(atab + (size_t)b * 8192);

    f32x4 acc0 = {0.f, 0.f, 0.f, 0.f};
    f32x4 acc1 = {0.f, 0.f, 0.f, 0.f};

    for (int ch = 0; ch < nch; ++ch) {
        short8 bv;
#pragma unroll
        for (int j = 0; j < 8; ++j) {
            int row = refl512(rowbase + 32 * ch + j);
            bv[j] = (short)src[(size_t)row * WW];
        }
        short8 ah0 = at[(ch * 4 + 0) * 64 + lane];
        short8 al0 = at[(ch * 4 + 1) * 64 + lane];
        short8 ah1 = at[(ch * 4 + 2) * 64 + lane];
        short8 al1 = at[(ch * 4 + 3) * 64 + lane];

        acc0 = __builtin_amdgcn_mfma_f32_16x16x32_bf16(ah0, bv, acc0, 0, 0, 0);
        acc0 = __builtin_amdgcn_mfma_f32_16x16x32_bf16(al0, bv, acc0, 0, 0, 0);
        acc1 = __builtin_amdgcn_mfma_f32_16x16x32_bf16(ah1, bv, acc1, 0, 0, 0);
        acc1 = __builtin_amdgcn_mfma_f32_16x16x32_bf16(al1, bv, acc1, 0, 0, 0);
    }

    const int orow = h0 + ((lane >> 4) << 2);
    float* dst = out + (size_t)bc * HH * WW + (size_t)orow * WW + w;
#pragma unroll
    for (int q = 0; q < 4; ++q) {
        __builtin_nontemporal_store(acc0[q], dst + (size_t)q * WW);
        __builtin_nontemporal_store(acc1[q], dst + (size_t)(q + 16) * WW);
    }
}

// ---------------------------------------------------------------------------
extern "C" void kernel_launch(void* const* d_in, const int* in_sizes, int n_in,
                              void* d_out, int out_size, void* d_ws, size_t ws_size,
                              hipStream_t stream)
{
    const float* x      = (const float*)d_in[0];
    const float* sigmas = (const float*)d_in[1];
    const int*   steps  = (const int*)d_in[2];
    float*       out    = (float*)d_out;

    int*      rbuf  = (int*)d_ws;                              // 256 B
    float*    mbuf  = (float*)((char*)d_ws + 256);             // 3 KB
    unsigned* ptab  = (unsigned*)((char*)d_ws + 4096);         // 32 KB pair tables
    u16*      atab  = (u16*)((char*)d_ws + 65536);             // 1 MiB A-frag table
    u16*      inter = (u16*)((char*)d_ws + 65536 + (1 << 20)); // 96 MiB bf16

    prep_kernel<<<64, 256, 0, stream>>>(sigmas, steps, rbuf, mbuf, ptab, atab);

    dim3 gB(HH / ROWS, BB);
    passB_kernel<<<gB, 256, 0, stream>>>(x, ptab, mbuf, rbuf, inter);

    dim3 gC(WW / 64, HH / 32, BB * CC);
    passC_kernel<<<gC, 256, 0, stream>>>(inter, atab, rbuf, out);
}